// Round 11
// baseline (348.082 us; speedup 1.0000x reference)
//
#include <hip/hip_runtime.h>
#include <hip/hip_bf16.h>
#include <math.h>

#define B_N 256
#define F_N 512
#define S_N 100000
#define Q_N 1024
#define EPSF 1e-12f
#define BM 128
#define NBLK ((S_N + BM - 1) / BM)   // 782 row-blocks
#define CAND_MAX 64
#define MARGIN 0.125f

typedef __attribute__((ext_vector_type(8))) short short8v;  // 8 bf16
typedef __attribute__((ext_vector_type(4))) float f32x4;

__device__ __forceinline__ unsigned short f2bf(float x) {  // RNE f32->bf16
  unsigned u = __float_as_uint(x);
  u = u + 0x7FFFu + ((u >> 16) & 1u);
  return (unsigned short)(u >> 16);
}

__device__ __forceinline__ float warpReduceSum(float v) {
  #pragma unroll
  for (int o = 32; o > 0; o >>= 1) v += __shfl_down(v, o);
  return v;
}

__device__ __forceinline__ float blockReduceSum256(float v, float* buf) {
  v = warpReduceSum(v);
  int lane = threadIdx.x & 63, w = threadIdx.x >> 6;
  __syncthreads();
  if (lane == 0) buf[w] = v;
  __syncthreads();
  return buf[0] + buf[1] + buf[2] + buf[3];
}

// convert 8 f32 -> hi bf16 fragment (4x v_cvt_pk_bf16_f32)
__device__ __forceinline__ void cvt8hi(const float4 a, const float4 b,
                                       short8v& hi) {
  union { unsigned u[4]; short8v v; } H;
  union { __hip_bfloat162 b2; unsigned u; } c;
  c.b2 = __float22bfloat162_rn(make_float2(a.x, a.y)); H.u[0] = c.u;
  c.b2 = __float22bfloat162_rn(make_float2(a.z, a.w)); H.u[1] = c.u;
  c.b2 = __float22bfloat162_rn(make_float2(b.x, b.y)); H.u[2] = c.u;
  c.b2 = __float22bfloat162_rn(make_float2(b.z, b.w)); H.u[3] = c.u;
  hi = H.v;
}

// -------- K0: L_norm; org -> (hi-only LINEAR bf16 plane + f32 copy); aug ----
// orghi[kt][col 256][slot 4][8]  (linear; no swizzle needed — no LDS anywhere)
__global__ __launch_bounds__(256) void k_prep(const float* __restrict__ V,
    const float* __restrict__ L, unsigned short* __restrict__ orghi,
    float* __restrict__ org, float* __restrict__ aug) {
  __shared__ float buf[4];
  int b = blockIdx.x, t = threadIdx.x;
  const float2 lv = *(const float2*)&L[b * F_N + t * 2];
  float ss = blockReduceSum256(lv.x * lv.x + lv.y * lv.y, buf);
  float invL = 1.0f / fmaxf(sqrtf(ss), EPSF);
  float lnx = lv.x * invL, lny = lv.y * invL;
  #pragma unroll
  for (int a = 0; a < 3; ++a) {
    const float2 vv = *(const float2*)&V[(a * B_N + b) * F_N + t * 2];
    float yx = vv.x * lnx, yy = vv.y * lny;
    float s2 = blockReduceSum256(yx * yx + yy * yy, buf);
    float inv = 1.0f / fmaxf(sqrtf(s2), EPSF);
    if (a == 0) {
      float ox = yx * inv, oy = yy * inv;
      int f = t * 2;
      int kt = f >> 5, kk = f & 31, sub = kk >> 3, pos = kk & 7;
      int off = kt * 8192 + b * 32 + sub * 8 + pos;
      ushort2 hv; hv.x = f2bf(ox); hv.y = f2bf(oy);
      *(ushort2*)&orghi[off] = hv;
      float2 of; of.x = ox; of.y = oy;
      *(float2*)&org[b * F_N + f] = of;
    } else {
      float* dst = &aug[((a - 1) * B_N + b) * F_N + t * 2];
      dst[0] = yx * inv;
      dst[1] = yy * inv;
    }
  }
}

// -------- K1: 1-pass hi*hi sims GEMM — BARRIER-FREE, LDS-FREE main loop.
// Block = 128 s-rows x 256 b-cols, 4 independent waves (32s x 256b each).
// A: HBM->reg + cvt_pk. B: orghi (256 KB, L2-resident) read DIRECTLY into
// MFMA regs via dwordx4 (each instr = contiguous 1KB line, perfect coalesce).
// No staging, no syncthreads in the loop -> no convoy; compiler free-pipes.
// Output: per-(block,b) max value -> blkmax[b][rowblk]. --------------------
__global__ __launch_bounds__(256, 2) void k_sims(const float* __restrict__ support,
    const unsigned short* __restrict__ orghi, float* __restrict__ blkmax) {
  __shared__ float wkf[1024];  // epilogue reduction only (4 KB)

  int t = threadIdx.x;
  int lane = t & 63, w = t >> 6;
  int r15 = lane & 15, ks = lane >> 4;
  int s0 = blockIdx.x * BM;

  f32x4 acc0[16], acc1[16];
  #pragma unroll
  for (int n = 0; n < 16; ++n) {
    acc0[n] = (f32x4){0.f, 0.f, 0.f, 0.f};
    acc1[n] = (f32x4){0.f, 0.f, 0.f, 0.f};
  }

  int row0 = s0 + w * 32 + r15;       // m=0
  int row1 = row0 + 16;               // m=1
  if (row0 > S_N - 1) row0 = S_N - 1;
  if (row1 > S_N - 1) row1 = S_N - 1;
  const float* ap0 = support + (size_t)row0 * F_N + ks * 8;
  const float* ap1 = support + (size_t)row1 * F_N + ks * 8;

  // per-lane B base: col = n*16 + r15, slot = ks ->
  // byte addr = kt*16384 + n*1024 + r15*64 + ks*16
  const unsigned char* bbase =
      (const unsigned char*)orghi + r15 * 64 + ks * 16;

  // prologue: A(0)
  float4 a0a = *(const float4*)(ap0);
  float4 a0b = *(const float4*)(ap0 + 4);
  float4 a1a = *(const float4*)(ap1);
  float4 a1b = *(const float4*)(ap1 + 4);

  #pragma unroll 1
  for (int kt = 0; kt < 16; ++kt) {
    short8v fh0, fh1;
    cvt8hi(a0a, a0b, fh0);
    cvt8hi(a1a, a1b, fh1);
    if (kt < 15) {  // 1-deep A prefetch (HBM latency hides under this kt)
      a0a = *(const float4*)(ap0 + (kt + 1) * 32);
      a0b = *(const float4*)(ap0 + (kt + 1) * 32 + 4);
      a1a = *(const float4*)(ap1 + (kt + 1) * 32);
      a1b = *(const float4*)(ap1 + (kt + 1) * 32 + 4);
    }
    const unsigned char* bp = bbase + kt * 16384;
    __builtin_amdgcn_s_setprio(1);
    #pragma unroll
    for (int n = 0; n < 16; ++n) {
      short8v bh = *(const short8v*)(bp + n * 1024);  // L2-hit global load
      acc0[n] = __builtin_amdgcn_mfma_f32_16x16x32_bf16(fh0, bh, acc0[n], 0, 0, 0);
      acc1[n] = __builtin_amdgcn_mfma_f32_16x16x32_bf16(fh1, bh, acc1[n], 0, 0, 0);
    }
    __builtin_amdgcn_s_setprio(0);
  }

  // ---- per-block column max (value only). C layout: col=lane&15. ----
  #pragma unroll
  for (int n = 0; n < 16; ++n) {
    float bv = -INFINITY;
    #pragma unroll
    for (int r = 0; r < 4; ++r) {
      bv = fmaxf(bv, acc0[n][r]);
      bv = fmaxf(bv, acc1[n][r]);
    }
    bv = fmaxf(bv, __shfl_xor(bv, 16));
    bv = fmaxf(bv, __shfl_xor(bv, 32));
    if (lane < 16) wkf[w * 256 + n * 16 + lane] = bv;
  }
  __syncthreads();
  {
    float m4 = fmaxf(fmaxf(wkf[t], wkf[256 + t]),
                     fmaxf(wkf[512 + t], wkf[768 + t]));
    blkmax[(size_t)t * NBLK + blockIdx.x] = m4;   // [b][rowblk]
  }
}

// -------- K1b: per-b candidate pick + exact f64 rescore (wave-per-row) -----
__global__ __launch_bounds__(256) void k_picknn(const float* __restrict__ support,
    const float* __restrict__ org, const float* __restrict__ blkmax,
    int* __restrict__ nnidx) {
  __shared__ float orgs[F_N];
  __shared__ float redf[4];
  __shared__ int lcand[CAND_MAX];
  __shared__ int lcnt;
  __shared__ double rv[4];
  __shared__ int ri[4];
  int b = blockIdx.x, t = threadIdx.x;
  int lane = t & 63, w = t >> 6;

  orgs[t] = org[b * F_N + t];
  orgs[256 + t] = org[b * F_N + 256 + t];
  if (t == 0) lcnt = 0;

  const float* bm = blkmax + (size_t)b * NBLK;
  float mx = -INFINITY;
  for (int rb = t; rb < NBLK; rb += 256) mx = fmaxf(mx, bm[rb]);
  #pragma unroll
  for (int o = 32; o > 0; o >>= 1) mx = fmaxf(mx, __shfl_xor(mx, o));
  __syncthreads();
  if (lane == 0) redf[w] = mx;
  __syncthreads();
  mx = fmaxf(fmaxf(redf[0], redf[1]), fmaxf(redf[2], redf[3]));
  float thr = mx - MARGIN;

  for (int rb = t; rb < NBLK; rb += 256) {
    if (bm[rb] >= thr) {
      int sl = atomicAdd(&lcnt, 1);
      if (sl < CAND_MAX) lcand[sl] = rb;
    }
  }
  __syncthreads();
  int nc = lcnt < CAND_MAX ? lcnt : CAND_MAX;

  // wave-per-row exact rescore: lane-parallel float4 loads, f64 butterfly
  double bv = -1e300;
  int bi = 0x7FFFFFFF;
  for (int rr = w; rr < nc * BM; rr += 4) {
    int s = lcand[rr >> 7] * BM + (rr & (BM - 1));
    if (s >= S_N) continue;
    const float4* rp = (const float4*)(support + (size_t)s * F_N) + lane * 2;
    float4 r0 = rp[0], r1 = rp[1];
    const float4 n0 = *(const float4*)&orgs[lane * 8];
    const float4 n1 = *(const float4*)&orgs[lane * 8 + 4];
    double d = (double)r0.x * (double)n0.x + (double)r0.y * (double)n0.y +
               (double)r0.z * (double)n0.z + (double)r0.w * (double)n0.w +
               (double)r1.x * (double)n1.x + (double)r1.y * (double)n1.y +
               (double)r1.z * (double)n1.z + (double)r1.w * (double)n1.w;
    #pragma unroll
    for (int o = 32; o > 0; o >>= 1) d += __shfl_xor(d, o);
    if (d > bv || (d == bv && s < bi)) { bv = d; bi = s; }
  }
  if (lane == 0) { rv[w] = bv; ri[w] = bi; }
  __syncthreads();
  if (t == 0) {
    double fv = rv[0]; int fi = ri[0];
    #pragma unroll
    for (int i = 1; i < 4; ++i)
      if (rv[i] > fv || (rv[i] == fv && ri[i] < fi)) { fv = rv[i]; fi = ri[i]; }
    nnidx[b] = fi;
  }
}

// -------- K2: nn = normalize(support[nn_idx]); batch_den --------
__global__ __launch_bounds__(256) void k_nn(const float* __restrict__ support,
    const int* __restrict__ nnidx, const float* __restrict__ aug,
    float* __restrict__ nn, float* __restrict__ bden) {
  __shared__ float buf[4];
  int b = blockIdx.x, t = threadIdx.x;
  int idx = nnidx[b];
  const float2 rv = *(const float2*)&support[(size_t)idx * F_N + t * 2];
  float ss = blockReduceSum256(rv.x * rv.x + rv.y * rv.y, buf);
  float inv = 1.0f / fmaxf(sqrtf(ss), EPSF);
  float nx = rv.x * inv, ny = rv.y * inv;
  nn[b * F_N + t * 2] = nx;
  nn[b * F_N + t * 2 + 1] = ny;
  const float2 a0 = *(const float2*)&aug[(0 * B_N + b) * F_N + t * 2];
  const float2 a1 = *(const float2*)&aug[(1 * B_N + b) * F_N + t * 2];
  float d0 = blockReduceSum256(a0.x * nx + a0.y * ny, buf);
  float d1 = blockReduceSum256(a1.x * nx + a1.y * ny, buf);
  if (t == 0) bden[b] = expf(d0 * 10.0f) + expf(d1 * 10.0f);
}

// -------- K3: queue dots, 4 blocks per b (chunk c of 256 q each) --------
__global__ __launch_bounds__(256) void k_qdot(const float* __restrict__ support,
    const float* __restrict__ gps, const float* __restrict__ sgps,
    const float* __restrict__ nn, double* __restrict__ qpart) {
  __shared__ float nns[F_N];
  __shared__ int qi[256];
  __shared__ int wtot[4];
  __shared__ double wacc[4];
  int b = blockIdx.x >> 2, c = blockIdx.x & 3;
  int t = threadIdx.x;
  int lane = t & 63, w = t >> 6;

  *(float2*)&nns[t * 2] = *(const float2*)&nn[b * F_N + t * 2];

  const float DEG2RAD = 0.017453292519943295f;
  float la = gps[b * 2] * DEG2RAD;
  float lo = gps[b * 2 + 1] * DEG2RAD;
  float ca = cosf(la);
  double xd = 25.0 / (2.0 * 6371.0088);
  float hcut = (float)(sin(xd) * sin(xd));  // dist>25km  <=>  h > hcut

  int cnt = 0;
  int qlo = c * 256;
  for (int base = 0; base < S_N; base += 256) {
    int s = base + t;
    bool far = false;
    if (s < S_N) {
      float lb = sgps[s * 2] * DEG2RAD;
      float ob = sgps[s * 2 + 1] * DEG2RAD;
      float sl = sinf((lb - la) * 0.5f);
      float so = sinf((ob - lo) * 0.5f);
      float h = sl * sl + ca * cosf(lb) * so * so;
      far = h > hcut;
    }
    unsigned long long m = __ballot(far);
    if (lane == 0) wtot[w] = (int)__popcll(m);
    __syncthreads();
    int offs = cnt;
    for (int wi = 0; wi < w; ++wi) offs += wtot[wi];
    if (far) {
      int pos = offs + (int)__popcll(m & ((1ull << lane) - 1ull));
      int rel = pos - qlo;
      if (rel >= 0 && rel < 256) qi[rel] = s;
    }
    cnt += wtot[0] + wtot[1] + wtot[2] + wtot[3];
    __syncthreads();
    if (cnt >= Q_N) break;
  }
  int nvalid = cnt < Q_N ? cnt : Q_N;
  __syncthreads();

  double acc = 0.0;
  for (int j = 0; j < 64; ++j) {
    int q = qlo + w * 64 + j;
    if (q >= nvalid) break;
    int row = qi[w * 64 + j];
    const float4* rp = (const float4*)&support[(size_t)row * F_N + lane * 8];
    float4 r0 = rp[0], r1 = rp[1];
    const float4 n0 = *(const float4*)&nns[lane * 8];
    const float4 n1 = *(const float4*)&nns[lane * 8 + 4];
    float dot = r0.x * n0.x + r0.y * n0.y + r0.z * n0.z + r0.w * n0.w +
                r1.x * n1.x + r1.y * n1.y + r1.z * n1.z + r1.w * n1.w;
    float ssq = r0.x * r0.x + r0.y * r0.y + r0.z * r0.z + r0.w * r0.w +
                r1.x * r1.x + r1.y * r1.y + r1.z * r1.z + r1.w * r1.w;
    #pragma unroll
    for (int o = 32; o > 0; o >>= 1) {
      dot += __shfl_xor(dot, o);
      ssq += __shfl_xor(ssq, o);
    }
    float val = dot / fmaxf(sqrtf(ssq), EPSF);
    acc += (double)expf(val * 10.0f);
  }
  if (lane == 0) wacc[w] = acc;
  __syncthreads();
  if (t == 0) {
    int got = nvalid - qlo;                 // valid q in this chunk
    if (got < 0) got = 0; if (got > 256) got = 256;
    int inval = 256 - got;                  // zero rows contribute exp(0)=1
    qpart[blockIdx.x] = wacc[0] + wacc[1] + wacc[2] + wacc[3] + (double)inval;
  }
}

// -------- K4: fold qpart + bden -> loss --------
__global__ __launch_bounds__(256) void k_final(const double* __restrict__ qpart,
    const float* __restrict__ bden, float* __restrict__ out) {
  __shared__ double buf[4];
  int t = threadIdx.x;
  double qd = qpart[t * 4] + qpart[t * 4 + 1] + qpart[t * 4 + 2] + qpart[t * 4 + 3];
  double bd = (double)bden[t];
  double v = -bd / (bd + qd);
  #pragma unroll
  for (int o = 32; o > 0; o >>= 1) v += __shfl_down(v, o);
  if ((t & 63) == 0) buf[t >> 6] = v;
  __syncthreads();
  if (t == 0) out[0] = (float)((buf[0] + buf[1] + buf[2] + buf[3]) / 256.0);
}

extern "C" void kernel_launch(void* const* d_in, const int* in_sizes, int n_in,
                              void* d_out, int out_size, void* d_ws, size_t ws_size,
                              hipStream_t stream) {
  const float* V = (const float*)d_in[0];
  const float* L = (const float*)d_in[1];
  const float* gps = (const float*)d_in[2];
  const float* support = (const float*)d_in[3];
  const float* sgps = (const float*)d_in[4];
  float* out = (float*)d_out;

  char* ws = (char*)d_ws;
  int* nnidx = (int*)ws;                                   // 1 KB @0
  float* bden = (float*)(ws + 2048);                       // 1 KB
  double* qpart = (double*)(ws + 4096);                    // 8 KB
  unsigned short* orghi = (unsigned short*)(ws + 12288);   // 256 KB
  float* org = (float*)(ws + 12288 + 262144);              // 512 KB
  float* aug = (float*)(ws + 12288 + 262144 + 524288);     // 1 MB
  float* nn = (float*)(ws + 12288 + 262144 + 524288 + 1048576);      // 512 KB
  float* blkmax = (float*)(ws + 12288 + 262144 + 524288 + 1048576 + 524288); // 800KB

  k_prep<<<256, 256, 0, stream>>>(V, L, orghi, org, aug);
  k_sims<<<NBLK, 256, 0, stream>>>(support, orghi, blkmax);
  k_picknn<<<256, 256, 0, stream>>>(support, org, blkmax, nnidx);
  k_nn<<<256, 256, 0, stream>>>(support, nnidx, aug, nn, bden);
  k_qdot<<<1024, 256, 0, stream>>>(support, gps, sgps, nn, qpart);
  k_final<<<1, 256, 0, stream>>>(qpart, bden, out);
}

// Round 12
// 167.205 us; speedup vs baseline: 2.0818x; 2.0818x over previous
//
#include <hip/hip_runtime.h>
#include <hip/hip_bf16.h>
#include <math.h>

#define B_N 256
#define F_N 512
#define S_N 100000
#define Q_N 1024
#define EPSF 1e-12f
#define BM 128
#define NBLK ((S_N + BM - 1) / BM)   // 782 row-blocks
#define CAND_MAX 64
#define MARGIN 0.125f
#define RS_SPLIT 16                  // rescore blocks per b

typedef __attribute__((ext_vector_type(8))) short short8v;  // 8 bf16
typedef __attribute__((ext_vector_type(4))) float f32x4;

__device__ __forceinline__ unsigned short f2bf(float x) {  // RNE f32->bf16
  unsigned u = __float_as_uint(x);
  u = u + 0x7FFFu + ((u >> 16) & 1u);
  return (unsigned short)(u >> 16);
}

__device__ __forceinline__ float warpReduceSum(float v) {
  #pragma unroll
  for (int o = 32; o > 0; o >>= 1) v += __shfl_down(v, o);
  return v;
}

__device__ __forceinline__ float blockReduceSum256(float v, float* buf) {
  v = warpReduceSum(v);
  int lane = threadIdx.x & 63, w = threadIdx.x >> 6;
  __syncthreads();
  if (lane == 0) buf[w] = v;
  __syncthreads();
  return buf[0] + buf[1] + buf[2] + buf[3];
}

__device__ __forceinline__ void async_copy16(void* lds, const void* g) {
  __builtin_amdgcn_global_load_lds(
      (const __attribute__((address_space(1))) unsigned int*)g,
      (__attribute__((address_space(3))) unsigned int*)lds, 16, 0, 0);
}

// convert 8 f32 -> hi bf16 fragment (4x v_cvt_pk_bf16_f32)
__device__ __forceinline__ void cvt8hi(const float4 a, const float4 b,
                                       short8v& hi) {
  union { unsigned u[4]; short8v v; } H;
  union { __hip_bfloat162 b2; unsigned u; } c;
  c.b2 = __float22bfloat162_rn(make_float2(a.x, a.y)); H.u[0] = c.u;
  c.b2 = __float22bfloat162_rn(make_float2(a.z, a.w)); H.u[1] = c.u;
  c.b2 = __float22bfloat162_rn(make_float2(b.x, b.y)); H.u[2] = c.u;
  c.b2 = __float22bfloat162_rn(make_float2(b.z, b.w)); H.u[3] = c.u;
  hi = H.v;
}

// -------- K0: L_norm; org -> (hi-only LINEAR bf16 plane + f32 copy); aug ----
// orghi[kt16][col 256][slot 4][8]  (linear)
__global__ __launch_bounds__(256) void k_prep(const float* __restrict__ V,
    const float* __restrict__ L, unsigned short* __restrict__ orghi,
    float* __restrict__ org, float* __restrict__ aug) {
  __shared__ float buf[4];
  int b = blockIdx.x, t = threadIdx.x;
  const float2 lv = *(const float2*)&L[b * F_N + t * 2];
  float ss = blockReduceSum256(lv.x * lv.x + lv.y * lv.y, buf);
  float invL = 1.0f / fmaxf(sqrtf(ss), EPSF);
  float lnx = lv.x * invL, lny = lv.y * invL;
  #pragma unroll
  for (int a = 0; a < 3; ++a) {
    const float2 vv = *(const float2*)&V[(a * B_N + b) * F_N + t * 2];
    float yx = vv.x * lnx, yy = vv.y * lny;
    float s2 = blockReduceSum256(yx * yx + yy * yy, buf);
    float inv = 1.0f / fmaxf(sqrtf(s2), EPSF);
    if (a == 0) {
      float ox = yx * inv, oy = yy * inv;
      int f = t * 2;
      int kt = f >> 5, kk = f & 31, sub = kk >> 3, pos = kk & 7;
      int off = kt * 8192 + b * 32 + sub * 8 + pos;
      ushort2 hv; hv.x = f2bf(ox); hv.y = f2bf(oy);
      *(ushort2*)&orghi[off] = hv;
      float2 of; of.x = ox; of.y = oy;
      *(float2*)&org[b * F_N + f] = of;
    } else {
      float* dst = &aug[((a - 1) * B_N + b) * F_N + t * 2];
      dst[0] = yx * inv;
      dst[1] = yy * inv;
    }
  }
}

// -------- K1: 1-pass hi*hi sims GEMM, BK=64 (8 rendezvous, was 16).
// Block = 128 s-rows x 256 b-cols, 4 waves (32s x 256b each). A: HBM->reg
// + cvt_pk. B: LDS dbuf 2x32KB via gload_lds (stage 32KB contiguous/iter),
// counted vmcnt(8) + raw barrier (A loads stay in flight). Output: blkmax. --
__global__ __launch_bounds__(256, 2) void k_sims(const float* __restrict__ support,
    const unsigned short* __restrict__ orghi, float* __restrict__ blkmax) {
  __shared__ __align__(16) unsigned char smem[65536];  // B dbuf 2x32KB

  int t = threadIdx.x;
  int lane = t & 63, w = t >> 6;
  int r15 = lane & 15, ks = lane >> 4;
  int s0 = blockIdx.x * BM;

  f32x4 acc0[16], acc1[16];
  #pragma unroll
  for (int n = 0; n < 16; ++n) {
    acc0[n] = (f32x4){0.f, 0.f, 0.f, 0.f};
    acc1[n] = (f32x4){0.f, 0.f, 0.f, 0.f};
  }

  int row0 = s0 + w * 32 + r15;       // m=0
  int row1 = row0 + 16;               // m=1
  if (row0 > S_N - 1) row0 = S_N - 1;
  if (row1 > S_N - 1) row1 = S_N - 1;
  const float* ap0 = support + (size_t)row0 * F_N + ks * 8;
  const float* ap1 = support + (size_t)row1 * F_N + ks * 8;

  const unsigned char* bsrc = (const unsigned char*)orghi + t * 16;

  // prologue: stage iter0 (8 gload_lds = 32KB), then A(0) (8 dwordx4)
  {
    unsigned char* dst = smem + t * 16;
    #pragma unroll
    for (int p = 0; p < 8; ++p) async_copy16(dst + p * 4096, bsrc + p * 4096);
  }
  __builtin_amdgcn_sched_barrier(0);
  float4 a00a = *(const float4*)(ap0);
  float4 a00b = *(const float4*)(ap0 + 4);
  float4 a01a = *(const float4*)(ap0 + 32);
  float4 a01b = *(const float4*)(ap0 + 36);
  float4 a10a = *(const float4*)(ap1);
  float4 a10b = *(const float4*)(ap1 + 4);
  float4 a11a = *(const float4*)(ap1 + 32);
  float4 a11b = *(const float4*)(ap1 + 36);
  __builtin_amdgcn_sched_barrier(0);
  asm volatile("s_waitcnt vmcnt(8)" ::: "memory");  // stage(0) landed; A flying
  __builtin_amdgcn_s_barrier();
  __builtin_amdgcn_sched_barrier(0);

  const int rbase = r15 * 64 + ks * 16;

  #pragma unroll 1
  for (int it = 0; it < 8; ++it) {
    unsigned char* bbuf = smem + (it & 1) * 32768;
    // convert current A regs (implicit wait covers the 8 pending A loads)
    short8v f00, f01, f10, f11;
    cvt8hi(a00a, a00b, f00);
    cvt8hi(a01a, a01b, f01);
    cvt8hi(a10a, a10b, f10);
    cvt8hi(a11a, a11b, f11);
    if (it < 7) {
      // stage next 32KB (8 gload_lds, oldest outstanding)
      const unsigned char* src = bsrc + (it + 1) * 32768;
      unsigned char* dst = smem + ((it + 1) & 1) * 32768 + t * 16;
      #pragma unroll
      for (int p = 0; p < 8; ++p) async_copy16(dst + p * 4096, src + p * 4096);
      __builtin_amdgcn_sched_barrier(0);  // pin: stage before A-prefetch
      a00a = *(const float4*)(ap0 + (it + 1) * 64);
      a00b = *(const float4*)(ap0 + (it + 1) * 64 + 4);
      a01a = *(const float4*)(ap0 + (it + 1) * 64 + 32);
      a01b = *(const float4*)(ap0 + (it + 1) * 64 + 36);
      a10a = *(const float4*)(ap1 + (it + 1) * 64);
      a10b = *(const float4*)(ap1 + (it + 1) * 64 + 4);
      a11a = *(const float4*)(ap1 + (it + 1) * 64 + 32);
      a11b = *(const float4*)(ap1 + (it + 1) * 64 + 36);
      __builtin_amdgcn_sched_barrier(0);  // pin: loads issued before compute
    }
    // compute: 16 n-tiles x 2 m x 2 k-chunks
    const unsigned char* bp = bbuf + rbase;
    __builtin_amdgcn_s_setprio(1);
    #pragma unroll
    for (int n = 0; n < 16; ++n) {
      short8v bh0 = *(const short8v*)(bp + n * 1024);
      short8v bh1 = *(const short8v*)(bp + 16384 + n * 1024);
      acc0[n] = __builtin_amdgcn_mfma_f32_16x16x32_bf16(f00, bh0, acc0[n], 0, 0, 0);
      acc1[n] = __builtin_amdgcn_mfma_f32_16x16x32_bf16(f10, bh0, acc1[n], 0, 0, 0);
      acc0[n] = __builtin_amdgcn_mfma_f32_16x16x32_bf16(f01, bh1, acc0[n], 0, 0, 0);
      acc1[n] = __builtin_amdgcn_mfma_f32_16x16x32_bf16(f11, bh1, acc1[n], 0, 0, 0);
    }
    __builtin_amdgcn_s_setprio(0);
    __builtin_amdgcn_sched_barrier(0);
    if (it < 7) {
      // retire the 8 stage ops; keep the 8 A loads in flight
      asm volatile("s_waitcnt vmcnt(8)" ::: "memory");
      __builtin_amdgcn_s_barrier();
    } else {
      __syncthreads();
    }
    __builtin_amdgcn_sched_barrier(0);
  }

  // ---- per-block column max (value only). C layout: col=lane&15. ----
  float* wkf = (float*)smem;  // overlay
  #pragma unroll
  for (int n = 0; n < 16; ++n) {
    float bv = -INFINITY;
    #pragma unroll
    for (int r = 0; r < 4; ++r) {
      bv = fmaxf(bv, acc0[n][r]);
      bv = fmaxf(bv, acc1[n][r]);
    }
    bv = fmaxf(bv, __shfl_xor(bv, 16));
    bv = fmaxf(bv, __shfl_xor(bv, 32));
    if (lane < 16) wkf[w * 256 + n * 16 + lane] = bv;
  }
  __syncthreads();
  {
    float m4 = fmaxf(fmaxf(wkf[t], wkf[256 + t]),
                     fmaxf(wkf[512 + t], wkf[768 + t]));
    blkmax[(size_t)t * NBLK + blockIdx.x] = m4;   // [b][rowblk]
  }
}

// -------- K1b: per-b threshold + candidate block list --------
__global__ __launch_bounds__(256) void k_cand(const float* __restrict__ blkmax,
    int* __restrict__ cand, int* __restrict__ cnt) {
  __shared__ float redf[4];
  __shared__ int lcand[CAND_MAX];
  __shared__ int lcnt;
  int b = blockIdx.x, t = threadIdx.x;
  int lane = t & 63, w = t >> 6;
  if (t == 0) lcnt = 0;

  const float* bm = blkmax + (size_t)b * NBLK;
  float mx = -INFINITY;
  for (int rb = t; rb < NBLK; rb += 256) mx = fmaxf(mx, bm[rb]);
  #pragma unroll
  for (int o = 32; o > 0; o >>= 1) mx = fmaxf(mx, __shfl_xor(mx, o));
  __syncthreads();
  if (lane == 0) redf[w] = mx;
  __syncthreads();
  mx = fmaxf(fmaxf(redf[0], redf[1]), fmaxf(redf[2], redf[3]));
  float thr = mx - MARGIN;

  for (int rb = t; rb < NBLK; rb += 256) {
    if (bm[rb] >= thr) {
      int sl = atomicAdd(&lcnt, 1);
      if (sl < CAND_MAX) lcand[sl] = rb;
    }
  }
  __syncthreads();
  int nc = lcnt < CAND_MAX ? lcnt : CAND_MAX;
  if (t < CAND_MAX) cand[b * CAND_MAX + t] = (t < nc) ? lcand[t] : 0;
  if (t == 0) cnt[b] = nc;
}

// -------- K1c: parallel exact f64 rescore. Grid 256*RS_SPLIT blocks.
// Block (b, jj): candidate slots sl = jj>>1, jj>>1 + 8, ...; half = jj&1
// (rows half*64..+64). 4 waves x wave-per-row (16 rows each), coalesced. ----
__global__ __launch_bounds__(256) void k_rescore(const float* __restrict__ support,
    const float* __restrict__ org, const int* __restrict__ cand,
    const int* __restrict__ cnt, double* __restrict__ rval,
    int* __restrict__ ridx) {
  __shared__ float orgs[F_N];
  __shared__ double rv[4];
  __shared__ int ri[4];
  int b = blockIdx.x >> 4, jj = blockIdx.x & (RS_SPLIT - 1);
  int t = threadIdx.x;
  int lane = t & 63, w = t >> 6;

  orgs[t] = org[b * F_N + t];
  orgs[256 + t] = org[b * F_N + 256 + t];
  __syncthreads();

  int nc = cnt[b];
  double bv = -1e300;
  int bi = 0x7FFFFFFF;
  for (int sl = (jj >> 1); sl < nc; sl += RS_SPLIT / 2) {
    int blk = cand[b * CAND_MAX + sl];
    int rbase = blk * BM + (jj & 1) * 64 + w * 16;
    for (int rr = 0; rr < 16; ++rr) {
      int s = rbase + rr;
      if (s >= S_N) continue;
      const float4* rp = (const float4*)(support + (size_t)s * F_N) + lane * 2;
      float4 r0 = rp[0], r1 = rp[1];
      const float4 n0 = *(const float4*)&orgs[lane * 8];
      const float4 n1 = *(const float4*)&orgs[lane * 8 + 4];
      double d = (double)r0.x * (double)n0.x + (double)r0.y * (double)n0.y +
                 (double)r0.z * (double)n0.z + (double)r0.w * (double)n0.w +
                 (double)r1.x * (double)n1.x + (double)r1.y * (double)n1.y +
                 (double)r1.z * (double)n1.z + (double)r1.w * (double)n1.w;
      #pragma unroll
      for (int o = 32; o > 0; o >>= 1) d += __shfl_xor(d, o);
      if (d > bv || (d == bv && s < bi)) { bv = d; bi = s; }
    }
  }
  if (lane == 0) { rv[w] = bv; ri[w] = bi; }
  __syncthreads();
  if (t == 0) {
    double fv = rv[0]; int fi = ri[0];
    #pragma unroll
    for (int i = 1; i < 4; ++i)
      if (rv[i] > fv || (rv[i] == fv && ri[i] < fi)) { fv = rv[i]; fi = ri[i]; }
    rval[b * RS_SPLIT + jj] = fv;
    ridx[b * RS_SPLIT + jj] = fi;
  }
}

// -------- K2: fold rescore slots -> nn_idx; nn = normalize; batch_den ------
__global__ __launch_bounds__(256) void k_nn(const float* __restrict__ support,
    const double* __restrict__ rval, const int* __restrict__ ridx,
    const float* __restrict__ aug, float* __restrict__ nn,
    float* __restrict__ bden) {
  __shared__ float buf[4];
  __shared__ int sidx;
  int b = blockIdx.x, t = threadIdx.x;
  if (t < 64) {
    double v = (t < RS_SPLIT) ? rval[b * RS_SPLIT + t] : -1e300;
    int i = (t < RS_SPLIT) ? ridx[b * RS_SPLIT + t] : 0x7FFFFFFF;
    #pragma unroll
    for (int o = 32; o > 0; o >>= 1) {
      double ov = __shfl_xor(v, o);
      int oi = __shfl_xor(i, o);
      if (ov > v || (ov == v && oi < i)) { v = ov; i = oi; }
    }
    if (t == 0) sidx = i;
  }
  __syncthreads();
  int idx = sidx;
  const float2 rvv = *(const float2*)&support[(size_t)idx * F_N + t * 2];
  float ss = blockReduceSum256(rvv.x * rvv.x + rvv.y * rvv.y, buf);
  float inv = 1.0f / fmaxf(sqrtf(ss), EPSF);
  float nx = rvv.x * inv, ny = rvv.y * inv;
  nn[b * F_N + t * 2] = nx;
  nn[b * F_N + t * 2 + 1] = ny;
  const float2 a0 = *(const float2*)&aug[(0 * B_N + b) * F_N + t * 2];
  const float2 a1 = *(const float2*)&aug[(1 * B_N + b) * F_N + t * 2];
  float d0 = blockReduceSum256(a0.x * nx + a0.y * ny, buf);
  float d1 = blockReduceSum256(a1.x * nx + a1.y * ny, buf);
  if (t == 0) bden[b] = expf(d0 * 10.0f) + expf(d1 * 10.0f);
}

// -------- K3: queue dots, 4 blocks per b (chunk c of 256 q each) --------
__global__ __launch_bounds__(256) void k_qdot(const float* __restrict__ support,
    const float* __restrict__ gps, const float* __restrict__ sgps,
    const float* __restrict__ nn, double* __restrict__ qpart) {
  __shared__ float nns[F_N];
  __shared__ int qi[256];
  __shared__ int wtot[4];
  __shared__ double wacc[4];
  int b = blockIdx.x >> 2, c = blockIdx.x & 3;
  int t = threadIdx.x;
  int lane = t & 63, w = t >> 6;

  *(float2*)&nns[t * 2] = *(const float2*)&nn[b * F_N + t * 2];

  const float DEG2RAD = 0.017453292519943295f;
  float la = gps[b * 2] * DEG2RAD;
  float lo = gps[b * 2 + 1] * DEG2RAD;
  float ca = cosf(la);
  double xd = 25.0 / (2.0 * 6371.0088);
  float hcut = (float)(sin(xd) * sin(xd));  // dist>25km  <=>  h > hcut

  int cnt = 0;
  int qlo = c * 256;
  for (int base = 0; base < S_N; base += 256) {
    int s = base + t;
    bool far = false;
    if (s < S_N) {
      float lb = sgps[s * 2] * DEG2RAD;
      float ob = sgps[s * 2 + 1] * DEG2RAD;
      float sl = sinf((lb - la) * 0.5f);
      float so = sinf((ob - lo) * 0.5f);
      float h = sl * sl + ca * cosf(lb) * so * so;
      far = h > hcut;
    }
    unsigned long long m = __ballot(far);
    if (lane == 0) wtot[w] = (int)__popcll(m);
    __syncthreads();
    int offs = cnt;
    for (int wi = 0; wi < w; ++wi) offs += wtot[wi];
    if (far) {
      int pos = offs + (int)__popcll(m & ((1ull << lane) - 1ull));
      int rel = pos - qlo;
      if (rel >= 0 && rel < 256) qi[rel] = s;
    }
    cnt += wtot[0] + wtot[1] + wtot[2] + wtot[3];
    __syncthreads();
    if (cnt >= Q_N) break;
  }
  int nvalid = cnt < Q_N ? cnt : Q_N;
  __syncthreads();

  double acc = 0.0;
  for (int j = 0; j < 64; ++j) {
    int q = qlo + w * 64 + j;
    if (q >= nvalid) break;
    int row = qi[w * 64 + j];
    const float4* rp = (const float4*)&support[(size_t)row * F_N + lane * 8];
    float4 r0 = rp[0], r1 = rp[1];
    const float4 n0 = *(const float4*)&nns[lane * 8];
    const float4 n1 = *(const float4*)&nns[lane * 8 + 4];
    float dot = r0.x * n0.x + r0.y * n0.y + r0.z * n0.z + r0.w * n0.w +
                r1.x * n1.x + r1.y * n1.y + r1.z * n1.z + r1.w * n1.w;
    float ssq = r0.x * r0.x + r0.y * r0.y + r0.z * r0.z + r0.w * r0.w +
                r1.x * r1.x + r1.y * r1.y + r1.z * r1.z + r1.w * r1.w;
    #pragma unroll
    for (int o = 32; o > 0; o >>= 1) {
      dot += __shfl_xor(dot, o);
      ssq += __shfl_xor(ssq, o);
    }
    float val = dot / fmaxf(sqrtf(ssq), EPSF);
    acc += (double)expf(val * 10.0f);
  }
  if (lane == 0) wacc[w] = acc;
  __syncthreads();
  if (t == 0) {
    int got = nvalid - qlo;                 // valid q in this chunk
    if (got < 0) got = 0; if (got > 256) got = 256;
    int inval = 256 - got;                  // zero rows contribute exp(0)=1
    qpart[blockIdx.x] = wacc[0] + wacc[1] + wacc[2] + wacc[3] + (double)inval;
  }
}

// -------- K4: fold qpart + bden -> loss --------
__global__ __launch_bounds__(256) void k_final(const double* __restrict__ qpart,
    const float* __restrict__ bden, float* __restrict__ out) {
  __shared__ double buf[4];
  int t = threadIdx.x;
  double qd = qpart[t * 4] + qpart[t * 4 + 1] + qpart[t * 4 + 2] + qpart[t * 4 + 3];
  double bd = (double)bden[t];
  double v = -bd / (bd + qd);
  #pragma unroll
  for (int o = 32; o > 0; o >>= 1) v += __shfl_down(v, o);
  if ((t & 63) == 0) buf[t >> 6] = v;
  __syncthreads();
  if (t == 0) out[0] = (float)((buf[0] + buf[1] + buf[2] + buf[3]) / 256.0);
}

extern "C" void kernel_launch(void* const* d_in, const int* in_sizes, int n_in,
                              void* d_out, int out_size, void* d_ws, size_t ws_size,
                              hipStream_t stream) {
  const float* V = (const float*)d_in[0];
  const float* L = (const float*)d_in[1];
  const float* gps = (const float*)d_in[2];
  const float* support = (const float*)d_in[3];
  const float* sgps = (const float*)d_in[4];
  float* out = (float*)d_out;

  char* ws = (char*)d_ws;
  float* bden = (float*)(ws + 2048);                       // 1 KB
  double* qpart = (double*)(ws + 4096);                    // 8 KB
  int* cnt = (int*)(ws + 12288);                           // 1 KB
  int* cand = (int*)(ws + 16384);                          // 64 KB
  double* rval = (double*)(ws + 81920);                    // 32 KB
  int* ridx = (int*)(ws + 114688);                         // 16 KB
  unsigned short* orghi = (unsigned short*)(ws + 131072);  // 256 KB
  float* org = (float*)(ws + 131072 + 262144);             // 512 KB
  float* aug = (float*)(ws + 131072 + 262144 + 524288);    // 1 MB
  float* nn = (float*)(ws + 131072 + 262144 + 524288 + 1048576);   // 512 KB
  float* blkmax = (float*)(ws + 131072 + 262144 + 524288 + 1048576 + 524288);

  k_prep<<<256, 256, 0, stream>>>(V, L, orghi, org, aug);
  k_sims<<<NBLK, 256, 0, stream>>>(support, orghi, blkmax);
  k_cand<<<256, 256, 0, stream>>>(blkmax, cand, cnt);
  k_rescore<<<256 * RS_SPLIT, 256, 0, stream>>>(support, org, cand, cnt, rval, ridx);
  k_nn<<<256, 256, 0, stream>>>(support, rval, ridx, aug, nn, bden);
  k_qdot<<<1024, 256, 0, stream>>>(support, gps, sgps, nn, qpart);
  k_final<<<1, 256, 0, stream>>>(qpart, bden, out);
}